// Round 10
// baseline (265.052 us; speedup 1.0000x reference)
//
#include <hip/hip_runtime.h>
#include <hip/hip_fp16.h>

#define NN 50000
#define NE 800000
#define SLOPE 0.2f
#define NEG_INF (-1e30f)
#define SCAN_B 196   // ceil(NN/256)
#define ECAP 64      // cached edges per wave in node_fused

typedef _Float16 half8 __attribute__((ext_vector_type(8)));
typedef float f32x4 __attribute__((ext_vector_type(4)));
typedef unsigned int u32x4 __attribute__((ext_vector_type(4)));

__device__ __forceinline__ float lrelu(float v) { return v >= 0.f ? v : SLOPE * v; }

// ---------------- fused prep: zero counts + WTaug for both layers ----------------
// WTaug [144][128] fp16: row c<128 = W[:,c]; 128..135 = u_src; 136..143 = u_dst,
// where u_src[k][h] = sum_c W[k][16h+c]*a_src[h][c]  ((X@W)@a == X@(W@a)).
__global__ __launch_bounds__(256) void prep_all(
    const float* __restrict__ W1, const float* __restrict__ as1, const float* __restrict__ ad1,
    __half* __restrict__ WT1,
    const float* __restrict__ W2, const float* __restrict__ as2, const float* __restrict__ ad2,
    __half* __restrict__ WT2,
    int* __restrict__ counts)
{
    const int t0 = blockIdx.x * 256 + threadIdx.x;
    const int stride = gridDim.x * 256;
    for (int i = t0; i < NN; i += stride) counts[i] = 0;
    #pragma unroll
    for (int layer = 0; layer < 2; ++layer) {
        const float* W = layer ? W2 : W1;
        const float* as_ = layer ? as2 : as1;
        const float* ad_ = layer ? ad2 : ad1;
        __half* WT = layer ? WT2 : WT1;
        for (int idx = t0; idx < 1024; idx += stride) {   // (k,h) aug rows
            const int k = idx >> 3, h = idx & 7;
            float s1 = 0.f, s2 = 0.f;
            #pragma unroll
            for (int c = 0; c < 16; ++c) {
                const float w = W[k * 128 + h * 16 + c];
                s1 += w * as_[h * 16 + c];
                s2 += w * ad_[h * 16 + c];
            }
            WT[(size_t)(128 + h) * 128 + k] = (__half)s1;
            WT[(size_t)(136 + h) * 128 + k] = (__half)s2;
        }
        for (int idx = t0; idx < 16384; idx += stride) {  // transpose W
            const int k = idx >> 7, c = idx & 127;
            WT[(size_t)c * 128 + k] = (__half)W[idx];
        }
    }
}

// ---------------- MFMA GEMM: H16 = f16(X @ W), asrc/adst fused as cols 128..143 ----
// 64 rows/block (4 waves x 16 rows), 9 col-tiles of 16. No LDS, no barriers.
// k-permutation invariance: any lane->k map is correct as long as A/B agree.
// C/D layout (m89-verified): col=lane&15, row=4*(lane>>4)+reg.
template<bool F32IN>
__global__ __launch_bounds__(256) void mfma_gemm(
    const void* __restrict__ Xin, const __half* __restrict__ WT,
    __half* __restrict__ H16, float* __restrict__ asrc, float* __restrict__ adst)
{
    const int t = threadIdx.x;
    const int w = t >> 6;
    const int lane = t & 63;
    const int r16 = lane & 15;
    const int g = lane >> 4;
    const int rowStrip = blockIdx.x * 64 + w * 16;
    const int rowm = min(rowStrip + r16, NN - 1);

    half8 afr[4];
    if constexpr (F32IN) {
        const float* xr = (const float*)Xin + (size_t)rowm * 128;
        #pragma unroll
        for (int ks = 0; ks < 4; ++ks) {
            const int k0 = ks * 32 + 8 * g;
            const float4 p = *(const float4*)&xr[k0];
            const float4 q = *(const float4*)&xr[k0 + 4];
            half8 a;
            a[0] = (_Float16)p.x; a[1] = (_Float16)p.y; a[2] = (_Float16)p.z; a[3] = (_Float16)p.w;
            a[4] = (_Float16)q.x; a[5] = (_Float16)q.y; a[6] = (_Float16)q.z; a[7] = (_Float16)q.w;
            afr[ks] = a;
        }
    } else {
        const __half* xr = (const __half*)Xin + (size_t)rowm * 128;
        #pragma unroll
        for (int ks = 0; ks < 4; ++ks) {
            afr[ks] = *(const half8*)&xr[ks * 32 + 8 * g];
        }
    }

    for (int ct = 0; ct < 9; ++ct) {
        f32x4 acc = {0.f, 0.f, 0.f, 0.f};
        const __half* wrow = WT + (size_t)(ct * 16 + r16) * 128 + 8 * g;
        #pragma unroll
        for (int ks = 0; ks < 4; ++ks) {
            const half8 b = *(const half8*)&wrow[ks * 32];
            acc = __builtin_amdgcn_mfma_f32_16x16x32_f16(afr[ks], b, acc, 0, 0, 0);
        }
        if (ct < 8) {
            #pragma unroll
            for (int rr = 0; rr < 4; ++rr) {
                const int r = rowStrip + 4 * g + rr;
                if (r < NN) H16[(size_t)r * 128 + ct * 16 + r16] = (__half)acc[rr];
            }
        } else {
            #pragma unroll
            for (int rr = 0; rr < 4; ++rr) {
                const int r = rowStrip + 4 * g + rr;
                if (r < NN) {
                    if (r16 < 8) asrc[(size_t)r * 8 + r16] = acc[rr];
                    else         adst[(size_t)r * 8 + (r16 - 8)] = acc[rr];
                }
            }
        }
    }
}

// ---------------- CSR build ----------------
__global__ __launch_bounds__(256) void hist_dst(const int* __restrict__ dst,
                                                int* __restrict__ counts) {
    int e = blockIdx.x * 256 + threadIdx.x;
    if (e >= NE) return;
    int d = dst[e];
    if ((unsigned)d >= NN) d = 0;
    atomicAdd(&counts[d], 1);
}

__global__ __launch_bounds__(256) void block_sum(const int* __restrict__ counts,
                                                 int* __restrict__ bsum) {
    __shared__ int red[256];
    int t = threadIdx.x, i = blockIdx.x * 256 + t;
    red[t] = (i < NN) ? counts[i] : 0;
    __syncthreads();
    for (int s = 128; s > 0; s >>= 1) {
        if (t < s) red[t] += red[t + s];
        __syncthreads();
    }
    if (t == 0) bsum[blockIdx.x] = red[0];
}

__global__ __launch_bounds__(256) void scan_bsum(const int* __restrict__ bsum,
                                                 int* __restrict__ boff) {
    __shared__ int sh[256];
    int t = threadIdx.x;
    int v = (t < SCAN_B) ? bsum[t] : 0;
    sh[t] = v;
    __syncthreads();
    for (int d = 1; d < 256; d <<= 1) {
        int u = (t >= d) ? sh[t - d] : 0;
        __syncthreads();
        sh[t] += u;
        __syncthreads();
    }
    if (t < SCAN_B) boff[t] = sh[t] - v;   // exclusive
}

__global__ __launch_bounds__(256) void scan_final(
    const int* __restrict__ counts, const int* __restrict__ boff,
    int* __restrict__ off, int* __restrict__ cursor)
{
    __shared__ int sh[256];
    int t = threadIdx.x, i = blockIdx.x * 256 + t;
    int v = (i < NN) ? counts[i] : 0;
    sh[t] = v;
    __syncthreads();
    for (int d = 1; d < 256; d <<= 1) {
        int u = (t >= d) ? sh[t - d] : 0;
        __syncthreads();
        sh[t] += u;
        __syncthreads();
    }
    if (i < NN) {
        int o = boff[blockIdx.x] + sh[t] - v;
        off[i] = o;
        cursor[i] = o;
        if (i == NN - 1) off[NN] = o + v;
    }
}

// single int2 {e, s} per slot: one 8B random store (nontemporal) per edge
__global__ __launch_bounds__(256) void scatter_csr(
    const int* __restrict__ src, const int* __restrict__ dst,
    int* __restrict__ cursor, int2* __restrict__ csrES) {
    int e = blockIdx.x * 256 + threadIdx.x;
    if (e >= NE) return;
    int s = src[e], d = dst[e];
    if ((unsigned)s >= NN) s = 0;
    if ((unsigned)d >= NN) d = 0;
    int pos = atomicAdd(&cursor[d], 1);
    unsigned long long v = ((unsigned long long)(unsigned)s << 32) | (unsigned)e;
    __builtin_nontemporal_store(v, (unsigned long long*)&csrES[pos]);
}

// ---------------- fused per-node softmax + aggregate (one wave per node) ----------------
// Phase 2 gathers fp16 H rows: one quarter-wave (16 lanes x 8 halves) per edge row.
// OT: __half for layer-1 (re-read by gemm2, temporal), float+NT for final output.
template<typename OT, bool NTOUT>
__global__ __launch_bounds__(256) void node_fused(
    const int* __restrict__ off, const int2* __restrict__ csrES,
    const float* __restrict__ asrc, const float* __restrict__ adst,
    const __half* __restrict__ H16, const float* __restrict__ bias,
    float* __restrict__ alpha, OT* __restrict__ out)
{
    __shared__ float ecache[4][ECAP * 8];   // per-wave e-values [i][h]
    __shared__ int2  scache[4][ECAP];       // per-wave {e, s}
    const int w = threadIdx.x >> 6;         // wave within block
    int wid = (blockIdx.x * 256 + threadIdx.x) >> 6;
    if (wid >= NN) return;
    const int lane = threadIdx.x & 63;
    const int n = wid;
    const int p0 = off[n], p1 = off[n + 1];
    const int deg = p1 - p0;
    const int h = lane & 7;      // head (softmax lanes)
    const int el = lane >> 3;    // edge-local slot 0..7
    const float ad = adst[n * 8 + h];

    // phase 1: online (max, sum), caching e-values + {e,s} in LDS
    float m = NEG_INF, l = 0.f;
    for (int base = 0; base < deg; base += 8) {
        int i = base + el;
        if (i < deg) {
            int2 es = csrES[p0 + i];
            float v = lrelu(asrc[es.y * 8 + h] + ad);
            if (i < ECAP) {
                ecache[w][i * 8 + h] = v;
                if (h == 0) scache[w][i] = es;
            }
            float nm = fmaxf(m, v);
            l = l * __expf(m - nm) + __expf(v - nm);
            m = nm;
        }
    }
    #pragma unroll
    for (int msk = 8; msk <= 32; msk <<= 1) {
        float m2 = __shfl_xor(m, msk);
        float l2 = __shfl_xor(l, msk);
        float nm = fmaxf(m, m2);
        l = l * __expf(m - nm) + l2 * __expf(m2 - nm);
        m = nm;
    }
    const float inv = 1.f / (l + 1e-16f);

    // phase 2: alpha write (nontemporal: never re-read) + fp16 gather-aggregate.
    // Quarter q handles edge slots k%4==q; channels ql*8..ql*8+7.
    // Convergent loops only: uniform trip count, clamped shfl index,
    // branchless predication (divergent __shfl is UB — round-4 lesson).
    const int q  = lane >> 4;
    const int ql = lane & 15;
    const int hq = ql >> 1;          // head of this channel group
    float4 accA = make_float4(0.f, 0.f, 0.f, 0.f);
    float4 accB = make_float4(0.f, 0.f, 0.f, 0.f);
    for (int base = 0; base < deg; base += 8) {
        int i = base + el;
        float a = 0.f;
        int s = 0;
        if (i < deg) {
            int e;
            float v;
            if (i < ECAP) {
                int2 es = scache[w][i];
                e = es.x; s = es.y;
                v = ecache[w][i * 8 + h];
            } else {
                int2 es = csrES[p0 + i];
                e = es.x; s = es.y;
                v = lrelu(asrc[s * 8 + h] + ad);
            }
            a = __expf(v - m) * inv;
            __builtin_nontemporal_store(a, &alpha[(size_t)e * 8 + h]);
        }
        const int cnt = min(8, deg - base);
        for (int kb = 0; kb < cnt; kb += 4) {          // uniform trip count
            const int kw = kb + q;                     // this quarter's edge slot
            const int kc = min(kw, cnt - 1);           // clamped valid slot
            float ak = __shfl(a, kc * 8 + hq);
            int   sk = __shfl(s, kc * 8);
            const float am = (kw < cnt) ? ak : 0.f;    // branchless predication
            float4 raw = *(const float4*)&H16[(size_t)sk * 128 + ql * 8];
            const __half2* ph = (const __half2*)&raw;
            const float2 f0 = __half22float2(ph[0]);
            const float2 f1 = __half22float2(ph[1]);
            const float2 f2 = __half22float2(ph[2]);
            const float2 f3 = __half22float2(ph[3]);
            accA.x = fmaf(f0.x, am, accA.x);
            accA.y = fmaf(f0.y, am, accA.y);
            accA.z = fmaf(f1.x, am, accA.z);
            accA.w = fmaf(f1.y, am, accA.w);
            accB.x = fmaf(f2.x, am, accB.x);
            accB.y = fmaf(f2.y, am, accB.y);
            accB.z = fmaf(f3.x, am, accB.z);
            accB.w = fmaf(f3.y, am, accB.w);
        }
    }
    // combine quarters: lanes {ql, ql+16, ql+32, ql+48} hold same channels
    accA.x += __shfl_xor(accA.x, 16); accA.x += __shfl_xor(accA.x, 32);
    accA.y += __shfl_xor(accA.y, 16); accA.y += __shfl_xor(accA.y, 32);
    accA.z += __shfl_xor(accA.z, 16); accA.z += __shfl_xor(accA.z, 32);
    accA.w += __shfl_xor(accA.w, 16); accA.w += __shfl_xor(accA.w, 32);
    accB.x += __shfl_xor(accB.x, 16); accB.x += __shfl_xor(accB.x, 32);
    accB.y += __shfl_xor(accB.y, 16); accB.y += __shfl_xor(accB.y, 32);
    accB.z += __shfl_xor(accB.z, 16); accB.z += __shfl_xor(accB.z, 32);
    accB.w += __shfl_xor(accB.w, 16); accB.w += __shfl_xor(accB.w, 32);
    if (q == 0) {
        const float4 bva = *(const float4*)&bias[ql * 8];
        const float4 bvb = *(const float4*)&bias[ql * 8 + 4];
        const float o0 = accA.x + bva.x, o1 = accA.y + bva.y;
        const float o2 = accA.z + bva.z, o3 = accA.w + bva.w;
        const float o4 = accB.x + bvb.x, o5 = accB.y + bvb.y;
        const float o6 = accB.z + bvb.z, o7 = accB.w + bvb.w;
        if constexpr (sizeof(OT) == 4) {
            if constexpr (NTOUT) {
                f32x4 oa = {o0, o1, o2, o3}, ob = {o4, o5, o6, o7};
                __builtin_nontemporal_store(oa, (f32x4*)&out[(size_t)n * 128 + ql * 8]);
                __builtin_nontemporal_store(ob, (f32x4*)&out[(size_t)n * 128 + ql * 8 + 4]);
            } else {
                float4 oa = {o0, o1, o2, o3}, ob = {o4, o5, o6, o7};
                *(float4*)&out[(size_t)n * 128 + ql * 8]     = oa;
                *(float4*)&out[(size_t)n * 128 + ql * 8 + 4] = ob;
            }
        } else {
            __half2 p0h = __floats2half2_rn(o0, o1);
            __half2 p1h = __floats2half2_rn(o2, o3);
            __half2 p2h = __floats2half2_rn(o4, o5);
            __half2 p3h = __floats2half2_rn(o6, o7);
            u32x4 pk = {*(unsigned*)&p0h, *(unsigned*)&p1h, *(unsigned*)&p2h, *(unsigned*)&p3h};
            if constexpr (NTOUT) {
                __builtin_nontemporal_store(pk, (u32x4*)&out[(size_t)n * 128 + ql * 8]);
            } else {
                *(u32x4*)&out[(size_t)n * 128 + ql * 8] = pk;
            }
        }
    }
}

extern "C" void kernel_launch(void* const* d_in, const int* in_sizes, int n_in,
                              void* d_out, int out_size, void* d_ws, size_t ws_size,
                              hipStream_t stream)
{
    const float* x   = (const float*)d_in[0];
    const float* W1  = (const float*)d_in[1];
    const float* as1 = (const float*)d_in[2];
    const float* ad1 = (const float*)d_in[3];
    const float* b1  = (const float*)d_in[4];
    const float* W2  = (const float*)d_in[5];
    const float* as2 = (const float*)d_in[6];
    const float* ad2 = (const float*)d_in[7];
    const float* b2  = (const float*)d_in[8];
    const int*   ei  = (const int*)d_in[9];
    const int* srcp = ei;
    const int* dstp = ei + NE;

    float* outx   = (float*)d_out;            // [NN*128]
    float* alpha1 = outx + (size_t)NN * 128;  // [NE*8]
    float* alpha2 = alpha1 + (size_t)NE * 8;  // [NE*8]

    __half* h16 = (__half*)d_ws;                        // NN*128 halves
    __half* x1h = h16 + (size_t)NN * 128;               // NN*128 halves
    __half* wt1 = x1h + (size_t)NN * 128;               // 144*128 halves
    __half* wt2 = wt1 + (size_t)144 * 128;              // 144*128 halves
    float* asrc = (float*)(wt2 + (size_t)144 * 128);    // NN*8
    float* adst = asrc + (size_t)NN * 8;                // NN*8
    int* counts = (int*)(adst + (size_t)NN * 8);        // NN
    int* off    = counts + NN;                           // NN+1
    int* cursor = off + NN + 1;                          // NN
    int2* csrES = (int2*)(cursor + NN);                  // NE int2
    int* bsum   = (int*)(csrES + NE);                    // SCAN_B
    int* boff   = bsum + SCAN_B;                         // SCAN_B

    int gemmGrid = (NN + 63) / 64;
    int nodeGrid = (NN + 3) / 4;           // 4 waves (nodes) per 256-thread block
    int edgeGrid = (NE + 255) / 256;

    // ---- fused prep (zero counts + both WTaug) + CSR build ----
    prep_all<<<SCAN_B, 256, 0, stream>>>(W1, as1, ad1, wt1, W2, as2, ad2, wt2, counts);
    hist_dst<<<edgeGrid, 256, 0, stream>>>(dstp, counts);
    block_sum<<<SCAN_B, 256, 0, stream>>>(counts, bsum);
    scan_bsum<<<1, 256, 0, stream>>>(bsum, boff);
    scan_final<<<SCAN_B, 256, 0, stream>>>(counts, boff, off, cursor);
    scatter_csr<<<edgeGrid, 256, 0, stream>>>(srcp, dstp, cursor, csrES);

    // ---- layer 1 ----
    mfma_gemm<true><<<gemmGrid, 256, 0, stream>>>(x, wt1, h16, asrc, adst);
    node_fused<__half, false><<<nodeGrid, 256, 0, stream>>>(off, csrES, asrc, adst, h16, b1, alpha1, x1h);

    // ---- layer 2 ----
    mfma_gemm<false><<<gemmGrid, 256, 0, stream>>>(x1h, wt2, h16, asrc, adst);
    node_fused<float, true><<<nodeGrid, 256, 0, stream>>>(off, csrES, asrc, adst, h16, b2, alpha2, outx);
}

// Round 11
// 233.064 us; speedup vs baseline: 1.1372x; 1.1372x over previous
//
#include <hip/hip_runtime.h>
#include <hip/hip_fp16.h>

#define NN 50000
#define NE 800000
#define SLOPE 0.2f
#define NEG_INF (-1e30f)
#define SCAN_B 196   // ceil(NN/256)
#define ECAP 64      // cached edges per wave in node_fused

typedef _Float16 half8 __attribute__((ext_vector_type(8)));
typedef float f32x4 __attribute__((ext_vector_type(4)));
typedef unsigned int u32x4 __attribute__((ext_vector_type(4)));

__device__ __forceinline__ float lrelu(float v) { return v >= 0.f ? v : SLOPE * v; }

// ---------------- fused prep: zero counts + WTaug for both layers ----------------
// WTaug [144][128] fp16: row c<128 = W[:,c]; 128..135 = u_src; 136..143 = u_dst,
// where u_src[k][h] = sum_c W[k][16h+c]*a_src[h][c]  ((X@W)@a == X@(W@a)).
__global__ __launch_bounds__(256) void prep_all(
    const float* __restrict__ W1, const float* __restrict__ as1, const float* __restrict__ ad1,
    __half* __restrict__ WT1,
    const float* __restrict__ W2, const float* __restrict__ as2, const float* __restrict__ ad2,
    __half* __restrict__ WT2,
    int* __restrict__ counts)
{
    const int t0 = blockIdx.x * 256 + threadIdx.x;
    const int stride = gridDim.x * 256;
    for (int i = t0; i < NN; i += stride) counts[i] = 0;
    #pragma unroll
    for (int layer = 0; layer < 2; ++layer) {
        const float* W = layer ? W2 : W1;
        const float* as_ = layer ? as2 : as1;
        const float* ad_ = layer ? ad2 : ad1;
        __half* WT = layer ? WT2 : WT1;
        for (int idx = t0; idx < 1024; idx += stride) {   // (k,h) aug rows
            const int k = idx >> 3, h = idx & 7;
            float s1 = 0.f, s2 = 0.f;
            #pragma unroll
            for (int c = 0; c < 16; ++c) {
                const float w = W[k * 128 + h * 16 + c];
                s1 += w * as_[h * 16 + c];
                s2 += w * ad_[h * 16 + c];
            }
            WT[(size_t)(128 + h) * 128 + k] = (__half)s1;
            WT[(size_t)(136 + h) * 128 + k] = (__half)s2;
        }
        for (int idx = t0; idx < 16384; idx += stride) {  // transpose W
            const int k = idx >> 7, c = idx & 127;
            WT[(size_t)c * 128 + k] = (__half)W[idx];
        }
    }
}

// ---------------- MFMA GEMM: H16 = f16(X @ W), asrc/adst fused as cols 128..143 ----
// 64 rows/block (4 waves x 16 rows), 9 col-tiles of 16. No LDS, no barriers.
// k-permutation invariance: any lane->k map is correct as long as A/B agree.
// C/D layout (m89-verified): col=lane&15, row=4*(lane>>4)+reg.
template<bool F32IN>
__global__ __launch_bounds__(256) void mfma_gemm(
    const void* __restrict__ Xin, const __half* __restrict__ WT,
    __half* __restrict__ H16, float* __restrict__ asrc, float* __restrict__ adst)
{
    const int t = threadIdx.x;
    const int w = t >> 6;
    const int lane = t & 63;
    const int r16 = lane & 15;
    const int g = lane >> 4;
    const int rowStrip = blockIdx.x * 64 + w * 16;
    const int rowm = min(rowStrip + r16, NN - 1);

    half8 afr[4];
    if constexpr (F32IN) {
        const float* xr = (const float*)Xin + (size_t)rowm * 128;
        #pragma unroll
        for (int ks = 0; ks < 4; ++ks) {
            const int k0 = ks * 32 + 8 * g;
            const float4 p = *(const float4*)&xr[k0];
            const float4 q = *(const float4*)&xr[k0 + 4];
            half8 a;
            a[0] = (_Float16)p.x; a[1] = (_Float16)p.y; a[2] = (_Float16)p.z; a[3] = (_Float16)p.w;
            a[4] = (_Float16)q.x; a[5] = (_Float16)q.y; a[6] = (_Float16)q.z; a[7] = (_Float16)q.w;
            afr[ks] = a;
        }
    } else {
        const __half* xr = (const __half*)Xin + (size_t)rowm * 128;
        #pragma unroll
        for (int ks = 0; ks < 4; ++ks) {
            afr[ks] = *(const half8*)&xr[ks * 32 + 8 * g];
        }
    }

    for (int ct = 0; ct < 9; ++ct) {
        f32x4 acc = {0.f, 0.f, 0.f, 0.f};
        const __half* wrow = WT + (size_t)(ct * 16 + r16) * 128 + 8 * g;
        #pragma unroll
        for (int ks = 0; ks < 4; ++ks) {
            const half8 b = *(const half8*)&wrow[ks * 32];
            acc = __builtin_amdgcn_mfma_f32_16x16x32_f16(afr[ks], b, acc, 0, 0, 0);
        }
        if (ct < 8) {
            #pragma unroll
            for (int rr = 0; rr < 4; ++rr) {
                const int r = rowStrip + 4 * g + rr;
                if (r < NN) H16[(size_t)r * 128 + ct * 16 + r16] = (__half)acc[rr];
            }
        } else {
            #pragma unroll
            for (int rr = 0; rr < 4; ++rr) {
                const int r = rowStrip + 4 * g + rr;
                if (r < NN) {
                    if (r16 < 8) asrc[(size_t)r * 8 + r16] = acc[rr];
                    else         adst[(size_t)r * 8 + (r16 - 8)] = acc[rr];
                }
            }
        }
    }
}

// ---------------- CSR build ----------------
// hist + per-edge rank in one pass: atomicAdd returns this edge's rank within d.
__global__ __launch_bounds__(256) void hist_rank(
    const int* __restrict__ dst, int* __restrict__ counts, int* __restrict__ rank) {
    int e = blockIdx.x * 256 + threadIdx.x;
    if (e >= NE) return;
    int d = dst[e];
    if ((unsigned)d >= NN) d = 0;
    rank[e] = atomicAdd(&counts[d], 1);
}

__global__ __launch_bounds__(256) void block_sum(const int* __restrict__ counts,
                                                 int* __restrict__ bsum) {
    __shared__ int red[256];
    int t = threadIdx.x, i = blockIdx.x * 256 + t;
    red[t] = (i < NN) ? counts[i] : 0;
    __syncthreads();
    for (int s = 128; s > 0; s >>= 1) {
        if (t < s) red[t] += red[t + s];
        __syncthreads();
    }
    if (t == 0) bsum[blockIdx.x] = red[0];
}

__global__ __launch_bounds__(256) void scan_bsum(const int* __restrict__ bsum,
                                                 int* __restrict__ boff) {
    __shared__ int sh[256];
    int t = threadIdx.x;
    int v = (t < SCAN_B) ? bsum[t] : 0;
    sh[t] = v;
    __syncthreads();
    for (int d = 1; d < 256; d <<= 1) {
        int u = (t >= d) ? sh[t - d] : 0;
        __syncthreads();
        sh[t] += u;
        __syncthreads();
    }
    if (t < SCAN_B) boff[t] = sh[t] - v;   // exclusive
}

__global__ __launch_bounds__(256) void scan_final(
    const int* __restrict__ counts, const int* __restrict__ boff,
    int* __restrict__ off)
{
    __shared__ int sh[256];
    int t = threadIdx.x, i = blockIdx.x * 256 + t;
    int v = (i < NN) ? counts[i] : 0;
    sh[t] = v;
    __syncthreads();
    for (int d = 1; d < 256; d <<= 1) {
        int u = (t >= d) ? sh[t - d] : 0;
        __syncthreads();
        sh[t] += u;
        __syncthreads();
    }
    if (i < NN) {
        int o = boff[blockIdx.x] + sh[t] - v;
        off[i] = o;
        if (i == NN - 1) off[NN] = o + v;
    }
}

// placement WITHOUT atomics: pos = off[d] + rank[e]; fire-and-forget NT store.
__global__ __launch_bounds__(256) void place_csr(
    const int* __restrict__ src, const int* __restrict__ dst,
    const int* __restrict__ rank, const int* __restrict__ off,
    int2* __restrict__ csrES) {
    int e = blockIdx.x * 256 + threadIdx.x;
    if (e >= NE) return;
    int s = src[e], d = dst[e];
    if ((unsigned)s >= NN) s = 0;
    if ((unsigned)d >= NN) d = 0;
    int pos = off[d] + rank[e];
    unsigned long long v = ((unsigned long long)(unsigned)s << 32) | (unsigned)e;
    __builtin_nontemporal_store(v, (unsigned long long*)&csrES[pos]);
}

// ---------------- fused per-node softmax + aggregate (one wave per node) ----------------
// Phase 2 gathers fp16 H rows: one quarter-wave (16 lanes x 8 halves) per edge row.
// OT: __half for layer-1 (re-read by gemm2, temporal), float+NT for final output.
template<typename OT, bool NTOUT>
__global__ __launch_bounds__(256) void node_fused(
    const int* __restrict__ off, const int2* __restrict__ csrES,
    const float* __restrict__ asrc, const float* __restrict__ adst,
    const __half* __restrict__ H16, const float* __restrict__ bias,
    float* __restrict__ alpha, OT* __restrict__ out)
{
    __shared__ float ecache[4][ECAP * 8];   // per-wave e-values [i][h]
    __shared__ int2  scache[4][ECAP];       // per-wave {e, s}
    const int w = threadIdx.x >> 6;         // wave within block
    int wid = (blockIdx.x * 256 + threadIdx.x) >> 6;
    if (wid >= NN) return;
    const int lane = threadIdx.x & 63;
    const int n = wid;
    const int p0 = off[n], p1 = off[n + 1];
    const int deg = p1 - p0;
    const int h = lane & 7;      // head (softmax lanes)
    const int el = lane >> 3;    // edge-local slot 0..7
    const float ad = adst[n * 8 + h];

    // phase 1: online (max, sum), caching e-values + {e,s} in LDS
    float m = NEG_INF, l = 0.f;
    for (int base = 0; base < deg; base += 8) {
        int i = base + el;
        if (i < deg) {
            int2 es = csrES[p0 + i];
            float v = lrelu(asrc[es.y * 8 + h] + ad);
            if (i < ECAP) {
                ecache[w][i * 8 + h] = v;
                if (h == 0) scache[w][i] = es;
            }
            float nm = fmaxf(m, v);
            l = l * __expf(m - nm) + __expf(v - nm);
            m = nm;
        }
    }
    #pragma unroll
    for (int msk = 8; msk <= 32; msk <<= 1) {
        float m2 = __shfl_xor(m, msk);
        float l2 = __shfl_xor(l, msk);
        float nm = fmaxf(m, m2);
        l = l * __expf(m - nm) + l2 * __expf(m2 - nm);
        m = nm;
    }
    const float inv = 1.f / (l + 1e-16f);

    // phase 2: alpha write (nontemporal: never re-read) + fp16 gather-aggregate.
    // Quarter q handles edge slots k%4==q; channels ql*8..ql*8+7.
    // Convergent loops only: uniform trip count, clamped shfl index,
    // branchless predication (divergent __shfl is UB — round-4 lesson).
    const int q  = lane >> 4;
    const int ql = lane & 15;
    const int hq = ql >> 1;          // head of this channel group
    float4 accA = make_float4(0.f, 0.f, 0.f, 0.f);
    float4 accB = make_float4(0.f, 0.f, 0.f, 0.f);
    for (int base = 0; base < deg; base += 8) {
        int i = base + el;
        float a = 0.f;
        int s = 0;
        if (i < deg) {
            int e;
            float v;
            if (i < ECAP) {
                int2 es = scache[w][i];
                e = es.x; s = es.y;
                v = ecache[w][i * 8 + h];
            } else {
                int2 es = csrES[p0 + i];
                e = es.x; s = es.y;
                v = lrelu(asrc[s * 8 + h] + ad);
            }
            a = __expf(v - m) * inv;
            __builtin_nontemporal_store(a, &alpha[(size_t)e * 8 + h]);
        }
        const int cnt = min(8, deg - base);
        for (int kb = 0; kb < cnt; kb += 4) {          // uniform trip count
            const int kw = kb + q;                     // this quarter's edge slot
            const int kc = min(kw, cnt - 1);           // clamped valid slot
            float ak = __shfl(a, kc * 8 + hq);
            int   sk = __shfl(s, kc * 8);
            const float am = (kw < cnt) ? ak : 0.f;    // branchless predication
            float4 raw = *(const float4*)&H16[(size_t)sk * 128 + ql * 8];
            const __half2* ph = (const __half2*)&raw;
            const float2 f0 = __half22float2(ph[0]);
            const float2 f1 = __half22float2(ph[1]);
            const float2 f2 = __half22float2(ph[2]);
            const float2 f3 = __half22float2(ph[3]);
            accA.x = fmaf(f0.x, am, accA.x);
            accA.y = fmaf(f0.y, am, accA.y);
            accA.z = fmaf(f1.x, am, accA.z);
            accA.w = fmaf(f1.y, am, accA.w);
            accB.x = fmaf(f2.x, am, accB.x);
            accB.y = fmaf(f2.y, am, accB.y);
            accB.z = fmaf(f3.x, am, accB.z);
            accB.w = fmaf(f3.y, am, accB.w);
        }
    }
    // combine quarters: lanes {ql, ql+16, ql+32, ql+48} hold same channels
    accA.x += __shfl_xor(accA.x, 16); accA.x += __shfl_xor(accA.x, 32);
    accA.y += __shfl_xor(accA.y, 16); accA.y += __shfl_xor(accA.y, 32);
    accA.z += __shfl_xor(accA.z, 16); accA.z += __shfl_xor(accA.z, 32);
    accA.w += __shfl_xor(accA.w, 16); accA.w += __shfl_xor(accA.w, 32);
    accB.x += __shfl_xor(accB.x, 16); accB.x += __shfl_xor(accB.x, 32);
    accB.y += __shfl_xor(accB.y, 16); accB.y += __shfl_xor(accB.y, 32);
    accB.z += __shfl_xor(accB.z, 16); accB.z += __shfl_xor(accB.z, 32);
    accB.w += __shfl_xor(accB.w, 16); accB.w += __shfl_xor(accB.w, 32);
    if (q == 0) {
        const float4 bva = *(const float4*)&bias[ql * 8];
        const float4 bvb = *(const float4*)&bias[ql * 8 + 4];
        const float o0 = accA.x + bva.x, o1 = accA.y + bva.y;
        const float o2 = accA.z + bva.z, o3 = accA.w + bva.w;
        const float o4 = accB.x + bvb.x, o5 = accB.y + bvb.y;
        const float o6 = accB.z + bvb.z, o7 = accB.w + bvb.w;
        if constexpr (sizeof(OT) == 4) {
            if constexpr (NTOUT) {
                f32x4 oa = {o0, o1, o2, o3}, ob = {o4, o5, o6, o7};
                __builtin_nontemporal_store(oa, (f32x4*)&out[(size_t)n * 128 + ql * 8]);
                __builtin_nontemporal_store(ob, (f32x4*)&out[(size_t)n * 128 + ql * 8 + 4]);
            } else {
                float4 oa = {o0, o1, o2, o3}, ob = {o4, o5, o6, o7};
                *(float4*)&out[(size_t)n * 128 + ql * 8]     = oa;
                *(float4*)&out[(size_t)n * 128 + ql * 8 + 4] = ob;
            }
        } else {
            __half2 p0h = __floats2half2_rn(o0, o1);
            __half2 p1h = __floats2half2_rn(o2, o3);
            __half2 p2h = __floats2half2_rn(o4, o5);
            __half2 p3h = __floats2half2_rn(o6, o7);
            u32x4 pk = {*(unsigned*)&p0h, *(unsigned*)&p1h, *(unsigned*)&p2h, *(unsigned*)&p3h};
            if constexpr (NTOUT) {
                __builtin_nontemporal_store(pk, (u32x4*)&out[(size_t)n * 128 + ql * 8]);
            } else {
                *(u32x4*)&out[(size_t)n * 128 + ql * 8] = pk;
            }
        }
    }
}

extern "C" void kernel_launch(void* const* d_in, const int* in_sizes, int n_in,
                              void* d_out, int out_size, void* d_ws, size_t ws_size,
                              hipStream_t stream)
{
    const float* x   = (const float*)d_in[0];
    const float* W1  = (const float*)d_in[1];
    const float* as1 = (const float*)d_in[2];
    const float* ad1 = (const float*)d_in[3];
    const float* b1  = (const float*)d_in[4];
    const float* W2  = (const float*)d_in[5];
    const float* as2 = (const float*)d_in[6];
    const float* ad2 = (const float*)d_in[7];
    const float* b2  = (const float*)d_in[8];
    const int*   ei  = (const int*)d_in[9];
    const int* srcp = ei;
    const int* dstp = ei + NE;

    float* outx   = (float*)d_out;            // [NN*128]
    float* alpha1 = outx + (size_t)NN * 128;  // [NE*8]
    float* alpha2 = alpha1 + (size_t)NE * 8;  // [NE*8]

    __half* h16 = (__half*)d_ws;                        // NN*128 halves
    __half* x1h = h16 + (size_t)NN * 128;               // NN*128 halves
    __half* wt1 = x1h + (size_t)NN * 128;               // 144*128 halves
    __half* wt2 = wt1 + (size_t)144 * 128;              // 144*128 halves
    float* asrc = (float*)(wt2 + (size_t)144 * 128);    // NN*8
    float* adst = asrc + (size_t)NN * 8;                // NN*8
    int* counts = (int*)(adst + (size_t)NN * 8);        // NN
    int* off    = counts + NN;                           // NN+1
    int* rank   = off + NN + 1;                          // NE
    int2* csrES = (int2*)(rank + NE);                    // NE int2
    int* bsum   = (int*)(csrES + NE);                    // SCAN_B
    int* boff   = bsum + SCAN_B;                         // SCAN_B

    int gemmGrid = (NN + 63) / 64;
    int nodeGrid = (NN + 3) / 4;           // 4 waves (nodes) per 256-thread block
    int edgeGrid = (NE + 255) / 256;

    // ---- fused prep (zero counts + both WTaug) + CSR build ----
    prep_all<<<SCAN_B, 256, 0, stream>>>(W1, as1, ad1, wt1, W2, as2, ad2, wt2, counts);
    hist_rank<<<edgeGrid, 256, 0, stream>>>(dstp, counts, rank);
    block_sum<<<SCAN_B, 256, 0, stream>>>(counts, bsum);
    scan_bsum<<<1, 256, 0, stream>>>(bsum, boff);
    scan_final<<<SCAN_B, 256, 0, stream>>>(counts, boff, off);
    place_csr<<<edgeGrid, 256, 0, stream>>>(srcp, dstp, rank, off, csrES);

    // ---- layer 1 ----
    mfma_gemm<true><<<gemmGrid, 256, 0, stream>>>(x, wt1, h16, asrc, adst);
    node_fused<__half, false><<<nodeGrid, 256, 0, stream>>>(off, csrES, asrc, adst, h16, b1, alpha1, x1h);

    // ---- layer 2 ----
    mfma_gemm<false><<<gemmGrid, 256, 0, stream>>>(x1h, wt2, h16, asrc, adst);
    node_fused<float, true><<<nodeGrid, 256, 0, stream>>>(off, csrES, asrc, adst, h16, b2, alpha2, outx);
}